// Round 1
// baseline (850.527 us; speedup 1.0000x reference)
//
#include <hip/hip_runtime.h>

// BlockDiagonalConv2d: out[b, co*64+head, h, w] = bias[head,co] +
//   sum_{ci<4, kh<3, kw<3} W[head,co,ci,kh,kw] * x[b, ci*64+head, h+kh-1, w+kw-1]
// B=32, H=W=128, 64 heads, 4 in/out channels per head, zero padding.
//
// Memory-bound problem (1.07 GB traffic vs 9.7 GFLOP). Plan: single pass,
// LDS-tile x (read once + 2-row halo), write out once, all fp32 vector FMA.

#define TH 16            // output rows per block tile
#define LROWS (TH + 2)   // staged rows incl. halo
#define LSTRIDE 128      // floats per LDS row (no col halo; edges via shfl)
#define LCH (LROWS * LSTRIDE)   // floats per channel in LDS

__global__ __launch_bounds__(256, 4)
void bdconv_kernel(const float* __restrict__ x,
                   const float* __restrict__ weights,
                   const float* __restrict__ bias,
                   float* __restrict__ out)
{
    __shared__ float lds[4 * LCH];   // 4 ch * 18 * 128 * 4B = 36864 B

    const int tid  = threadIdx.x;
    const int bi   = blockIdx.x;
    const int tile = bi & 7;           // 8 row-tiles
    const int head = (bi >> 3) & 63;   // 64 heads
    const int b    = bi >> 9;          // 32 batches
    const int h0   = tile * TH;

    // ---- stage: 4 channels x 18 rows x 128 cols, coalesced float4 ----
    {
        const int seg = tid & 31;      // float4 segment within a row
        const int rg  = tid >> 5;      // 0..7
        const size_t bh_base = ((size_t)b * 256 + head) * (128 * 128);
        #pragma unroll
        for (int k = 0; k < 9; ++k) {
            const int rowid = rg + (k << 3);        // 0..71 flat (ch*18 + r)
            const int ch = rowid / LROWS;
            const int r  = rowid - ch * LROWS;
            const int h  = h0 - 1 + r;
            float4 v = make_float4(0.f, 0.f, 0.f, 0.f);
            if (h >= 0 && h < 128) {
                const float* p = x + bh_base + (size_t)ch * (64 * 128 * 128)
                                   + h * 128 + seg * 4;
                v = *reinterpret_cast<const float4*>(p);
            }
            *reinterpret_cast<float4*>(&lds[rowid * LSTRIDE + seg * 4]) = v;
        }
    }
    __syncthreads();

    // ---- compute: thread = (col group cg of 4 cols) x (2 rows) ----
    const int cg = tid & 31;       // 32 col groups
    const int tr = tid >> 5;       // 0..7 row-thread
    const int c4 = cg << 2;        // first output col
    const int r0 = tr << 1;        // first output row (within tile)

    const float* wp = weights + head * 144;   // [co][ci][kh][kw], uniform -> s_load

    float4 acc[2][4];
    #pragma unroll
    for (int co = 0; co < 4; ++co) {
        const float bv = bias[head * 4 + co];
        acc[0][co] = make_float4(bv, bv, bv, bv);
        acc[1][co] = make_float4(bv, bv, bv, bv);
    }

    #pragma unroll
    for (int ci = 0; ci < 4; ++ci) {
        // 4 input rows (r0-1+kh for kh in 0..2 over 2 output rows -> lds rows r0..r0+3)
        float f[4][6];
        #pragma unroll
        for (int j = 0; j < 4; ++j) {
            const float4 m = *reinterpret_cast<const float4*>(
                &lds[ci * LCH + (r0 + j) * LSTRIDE + c4]);
            // horizontal halo from neighbor lanes (lane-1 holds cols c4-4..c4-1)
            const float lu = __shfl_up(m.w, 1);
            const float ld = __shfl_down(m.x, 1);
            f[j][0] = (cg == 0)  ? 0.f : lu;   // w = c4-1
            f[j][1] = m.x; f[j][2] = m.y; f[j][3] = m.z; f[j][4] = m.w;
            f[j][5] = (cg == 31) ? 0.f : ld;   // w = c4+4
        }
        #pragma unroll
        for (int rr = 0; rr < 2; ++rr) {
            #pragma unroll
            for (int kh = 0; kh < 3; ++kh) {
                const float* frow = f[rr + kh];
                #pragma unroll
                for (int co = 0; co < 4; ++co) {
                    const float* wrow = wp + ((co * 4 + ci) * 3 + kh) * 3;
                    #pragma unroll
                    for (int kw = 0; kw < 3; ++kw) {
                        const float wv = wrow[kw];
                        acc[rr][co].x = fmaf(wv, frow[kw + 0], acc[rr][co].x);
                        acc[rr][co].y = fmaf(wv, frow[kw + 1], acc[rr][co].y);
                        acc[rr][co].z = fmaf(wv, frow[kw + 2], acc[rr][co].z);
                        acc[rr][co].w = fmaf(wv, frow[kw + 3], acc[rr][co].w);
                    }
                }
            }
        }
    }

    // ---- store: 2 rows x 4 output channels, coalesced float4 ----
    #pragma unroll
    for (int rr = 0; rr < 2; ++rr) {
        const int h = h0 + r0 + rr;
        #pragma unroll
        for (int co = 0; co < 4; ++co) {
            float* op = out + (((size_t)b * 256 + co * 64 + head) * 128 + h) * 128 + c4;
            *reinterpret_cast<float4*>(op) = acc[rr][co];
        }
    }
}

extern "C" void kernel_launch(void* const* d_in, const int* in_sizes, int n_in,
                              void* d_out, int out_size, void* d_ws, size_t ws_size,
                              hipStream_t stream) {
    const float* x       = (const float*)d_in[0];
    const float* weights = (const float*)d_in[1];
    const float* bias    = (const float*)d_in[2];
    float* out = (float*)d_out;

    // grid: 8 tiles * 64 heads * 32 batches = 16384 blocks of 256 threads
    dim3 grid(8 * 64 * 32);
    dim3 block(256);
    hipLaunchKernelGGL(bdconv_kernel, grid, block, 0, stream, x, weights, bias, out);
}